// Round 3
// baseline (55.229 us; speedup 1.0000x reference)
//
#include <hip/hip_runtime.h>
#include <math.h>

#define PI_F 3.14159265358979323846f

// QuantumProjection — R13: fused, barrier-free, in-wave software pipeline.
// R12 post-mortem: fused-with-barrier = 50.0us == split. VALU fixed (23%) but
// grid == residency (1024 blocks, 16 waves/CU) -> all waves in lockstep through
// {read burst, VALU circuit, write burst}; read & write streams never overlap.
// Serial-phase model: 10.5 (FETCH 66MB) + ~4 (circuit) + 21 (WRITE 131MB) + congestion = 50us.
// Floor = 197MB @ 6.3 TB/s mixed = ~31us.
// R13 changes (stream mixing, one variable at a time conceptually = "overlap"):
//  1. Each wave owns 32 samples = 2 tiles x 16; dot-pass loads prefetched 2 deep,
//     so 16KB of reads is in flight across each tile's circuit+GEMM+stores.
//  2. LDS+__syncthreads hand-off replaced by shuffle redistribution (fold results
//     are duplicated mod 16 across the wave; comb=pass[lane>>4] via 2 cndmask,
//     then __shfl from same-16-group src (lane&48)+4*((lane>>2)&3)+w). No barrier
//     -> waves drift freely; no LDS.
//  3. postW/postb loaded per-tile (L1-hot 8KB) instead of held: VGPR headroom.
// Kept: R7 (no launch_bounds reg cap), R9 (plain loads for x; L3 retains ~half),
// R10 (NT stores for the write-once out stream).

typedef float floatx4 __attribute__((ext_vector_type(4)));

static __device__ __forceinline__ void nt_store4(float* p, floatx4 v)
{
    __builtin_nontemporal_store(v, reinterpret_cast<floatx4*>(p));
}

static __device__ __forceinline__ float fast_tanh(float a)
{
    a = fminf(fmaxf(a, -15.f), 15.f);
    const float e = __expf(2.f * a);
    return (e - 1.f) / (e + 1.f);
}

// wire w lives at bit (3-w) of the 16-amp index
template<int WIRE>
__device__ __forceinline__ void apply1q(float* sr, float* si,
    float u00r, float u00i, float u01r, float u01i,
    float u10r, float u10i, float u11r, float u11i)
{
    constexpr int st = 1 << (3 - WIRE);
#pragma unroll
    for (int i = 0; i < 16; ++i) {
        if (i & st) continue;
        const int j = i | st;
        const float r0 = sr[i], m0 = si[i], r1 = sr[j], m1 = si[j];
        sr[i] = u00r * r0 - u00i * m0 + u01r * r1 - u01i * m1;
        si[i] = u00r * m0 + u00i * r0 + u01r * m1 + u01i * r1;
        sr[j] = u10r * r0 - u10i * m0 + u11r * r1 - u11i * m1;
        si[j] = u10r * m0 + u10i * r0 + u11r * m1 + u11i * r1;
    }
}

template<int CW, int TW>
__device__ __forceinline__ void cnot(float* sr, float* si)
{
    constexpr int cb = 1 << (3 - CW), tb = 1 << (3 - TW);
#pragma unroll
    for (int i = 0; i < 16; ++i) {
        if ((i & cb) && !(i & tb)) {
            const int j = i | tb;
            float t;
            t = sr[i]; sr[i] = sr[j]; sr[j] = t;
            t = si[i]; si[i] = si[j]; si[j] = t;
        }
    }
}

// Wave-uniform gate via v_sin/v_cos (args in (-pi, 2pi): no range reduction needed)
#define APPLY_FAST(L, W) { \
    const float ph = wts[((L) * 4 + (W)) * 3 + 0]; \
    const float th = wts[((L) * 4 + (W)) * 3 + 1]; \
    const float om = wts[((L) * 4 + (W)) * 3 + 2]; \
    const float s_  = __sinf(0.5f * th),        c_  = __cosf(0.5f * th); \
    const float sp_ = __sinf(0.5f * (ph + om)), cp_ = __cosf(0.5f * (ph + om)); \
    const float sq_ = __sinf(0.5f * (ph - om)), cq_ = __cosf(0.5f * (ph - om)); \
    apply1q<W>(sr, si, cp_ * c_, -sp_ * c_, -cq_ * s_, -sq_ * s_, \
                       cq_ * s_, -sq_ * s_, cp_ * c_,  sp_ * c_); }

// Issue one dot-pass's 8 float4 loads into buffer slot (p = pass index 0..7)
#define ISSUE_PASS(slot, p) { \
    const float* xr_ = x + (size_t)(wbase + (p) * 4) * 512 + lane * 4; \
    bxa[slot][0] = *reinterpret_cast<const float4*>(xr_); \
    bxb[slot][0] = *reinterpret_cast<const float4*>(xr_ + 256); \
    bxa[slot][1] = *reinterpret_cast<const float4*>(xr_ + 512); \
    bxb[slot][1] = *reinterpret_cast<const float4*>(xr_ + 768); \
    bxa[slot][2] = *reinterpret_cast<const float4*>(xr_ + 1024); \
    bxb[slot][2] = *reinterpret_cast<const float4*>(xr_ + 1280); \
    bxa[slot][3] = *reinterpret_cast<const float4*>(xr_ + 1536); \
    bxb[slot][3] = *reinterpret_cast<const float4*>(xr_ + 1792); }

// Consume buffer slot: 4 samples x 4 wires dot + 17-shfl fold -> one angle/lane.
// After xor16/xor32 the result is valid on ALL lanes (duplicated mod 16):
// lane l holds angle(sample 4*pass + ((l&15)>>2), wire l&3).
#define DOTS_FOLD(slot, dest) { \
    float acc[4][4]; \
    _Pragma("unroll") \
    for (int t = 0; t < 4; ++t) { \
        _Pragma("unroll") \
        for (int w = 0; w < 4; ++w) { \
            acc[t][w] = bxa[slot][t].x * wA[w].x + bxa[slot][t].y * wA[w].y \
                      + bxa[slot][t].z * wA[w].z + bxa[slot][t].w * wA[w].w \
                      + bxb[slot][t].x * wB[w].x + bxb[slot][t].y * wB[w].y \
                      + bxb[slot][t].z * wB[w].z + bxb[slot][t].w * wB[w].w; \
        } \
    } \
    float v[4]; \
    _Pragma("unroll") \
    for (int t = 0; t < 4; ++t) { \
        float a01 = (lane & 1) ? acc[t][1] : acc[t][0]; \
        float b01 = (lane & 1) ? acc[t][0] : acc[t][1]; \
        a01 += __shfl_xor(b01, 1, 64); \
        float a23 = (lane & 1) ? acc[t][3] : acc[t][2]; \
        float b23 = (lane & 1) ? acc[t][2] : acc[t][3]; \
        a23 += __shfl_xor(b23, 1, 64); \
        const float vv = (lane & 2) ? a23 : a01; \
        const float uu = (lane & 2) ? a01 : a23; \
        v[t] = vv + __shfl_xor(uu, 2, 64); \
    } \
    float c01 = (lane & 4) ? v[1] : v[0]; \
    float d01 = (lane & 4) ? v[0] : v[1]; \
    c01 += __shfl_xor(d01, 4, 64); \
    float c23 = (lane & 4) ? v[3] : v[2]; \
    float d23 = (lane & 4) ? v[2] : v[3]; \
    c23 += __shfl_xor(d23, 4, 64); \
    float m_ = (lane & 8) ? c23 : c01; \
    float n_ = (lane & 8) ? c01 : c23; \
    m_ += __shfl_xor(n_, 8, 64); \
    m_ += __shfl_xor(m_, 16, 64); \
    m_ += __shfl_xor(m_, 32, 64); \
    dest = fast_tanh(m_ + pbv) * PI_F; }

// Block = 256 threads = 4 waves; each wave owns 32 consecutive samples (2 tiles).
__global__ __launch_bounds__(256) void k_fused(
    const float* __restrict__ x,
    const float* __restrict__ preW,
    const float* __restrict__ preb,
    const float* __restrict__ wts,
    const float* __restrict__ postW,
    const float* __restrict__ postb,
    float* __restrict__ out, int B)
{
    const int lane  = threadIdx.x & 63;
    const int wid   = threadIdx.x >> 6;
    const int wbase = blockIdx.x * 128 + wid * 32;
    if (wbase >= B) return;

    // Held weights for the dot phase (preW = 8KB, L1-hot; 32 VGPR)
    float4 wA[4], wB[4];
#pragma unroll
    for (int w = 0; w < 4; ++w) {
        wA[w] = *reinterpret_cast<const float4*>(preW + w * 512 + lane * 4);
        wB[w] = *reinterpret_cast<const float4*>(preW + w * 512 + 256 + lane * 4);
    }
    const float4 pb = *reinterpret_cast<const float4*>(preb);
    const float pb01 = (lane & 1) ? pb.y : pb.x;
    const float pb23 = (lane & 1) ? pb.w : pb.z;
    const float pbv  = (lane & 2) ? pb23 : pb01;   // bias for wire lane&3

    float4 bxa[2][4], bxb[2][4];                   // 2-deep pass prefetch buffers

    // circuit + out-GEMM for one 16-sample tile; a0..a3 = fold results of its 4 passes
    auto tile_body = [&](int tb, float a0, float a1, float a2, float a3) {
        // ---- shuffle redistribution (replaces LDS+barrier) ----
        // lane l needs angles of sample sid=l>>2: pass p=sid>>2 == l>>4 == group G.
        // comb holds pass-G's value on every lane of group G; src lane stays in-group.
        const float comb = (lane & 32) ? ((lane & 16) ? a3 : a2)
                                       : ((lane & 16) ? a1 : a0);
        const int sb = (lane & 48) + 4 * ((lane >> 2) & 3);
        const float A0 = __shfl(comb, sb + 0, 64);
        const float A1 = __shfl(comb, sb + 1, 64);
        const float A2 = __shfl(comb, sb + 2, 64);
        const float A3 = __shfl(comb, sb + 3, 64);

        // postW/postb per tile (8KB, L1-hot; issued here, consumed after circuit)
        const float4* pW4 = reinterpret_cast<const float4*>(postW);
        const float4* pb4 = reinterpret_cast<const float4*>(postb);
        const float4 p0 = pW4[4 * lane + 0], p1 = pW4[4 * lane + 1];
        const float4 p2 = pW4[4 * lane + 2], p3 = pW4[4 * lane + 3];
        const float4 p4 = pW4[4 * (64 + lane) + 0], p5 = pW4[4 * (64 + lane) + 1];
        const float4 p6 = pW4[4 * (64 + lane) + 2], p7 = pW4[4 * (64 + lane) + 3];
        const float4 bb0 = pb4[lane], bb1 = pb4[64 + lane];

        // ---- RX embedding: amp[i] = prod_w (c_w or -i s_w) ----
        const float s0 = __sinf(0.5f * A0), c0 = __cosf(0.5f * A0);
        const float s1 = __sinf(0.5f * A1), c1 = __cosf(0.5f * A1);
        const float s2 = __sinf(0.5f * A2), c2 = __cosf(0.5f * A2);
        const float s3 = __sinf(0.5f * A3), c3 = __cosf(0.5f * A3);

        float sr[16], si[16];
#pragma unroll
        for (int i = 0; i < 16; ++i) {
            const float r = ((i & 8) ? s0 : c0) * ((i & 4) ? s1 : c1)
                          * ((i & 2) ? s2 : c2) * ((i & 1) ? s3 : c3);
            const int mm = (((i >> 3) & 1) + ((i >> 2) & 1) + ((i >> 1) & 1) + (i & 1)) & 3;
            switch (mm) {                // multiply by (-i)^popcount
                case 0:  sr[i] = r;    si[i] = 0.f; break;
                case 1:  sr[i] = 0.f;  si[i] = -r;  break;
                case 2:  sr[i] = -r;   si[i] = 0.f; break;
                default: sr[i] = 0.f;  si[i] = r;   break;
            }
        }

        APPLY_FAST(0, 0); APPLY_FAST(0, 1); APPLY_FAST(0, 2); APPLY_FAST(0, 3);
        cnot<0, 1>(sr, si); cnot<1, 2>(sr, si); cnot<2, 3>(sr, si); cnot<3, 0>(sr, si);
        APPLY_FAST(1, 0); APPLY_FAST(1, 1); APPLY_FAST(1, 2); APPLY_FAST(1, 3);
        cnot<0, 2>(sr, si); cnot<1, 3>(sr, si); cnot<2, 0>(sr, si); cnot<3, 1>(sr, si);

        float z0 = 0.f, z1 = 0.f, z2 = 0.f, z3 = 0.f;
#pragma unroll
        for (int i = 0; i < 16; ++i) {
            const float p = sr[i] * sr[i] + si[i] * si[i];
            z0 += (i & 8) ? -p : p;
            z1 += (i & 4) ? -p : p;
            z2 += (i & 2) ? -p : p;
            z3 += (i & 1) ? -p : p;
        }

        // ---- out GEMM: 16 rows, 2 coalesced NT float4 stores per lane per row ----
#pragma unroll
        for (int s = 0; s < 16; ++s) {
            const float q0 = __shfl(z0, s * 4, 64);
            const float q1 = __shfl(z1, s * 4, 64);
            const float q2 = __shfl(z2, s * 4, 64);
            const float q3 = __shfl(z3, s * 4, 64);
            floatx4 o0, o1;
            o0.x = fmaf(q3, p0.w, fmaf(q2, p0.z, fmaf(q1, p0.y, fmaf(q0, p0.x, bb0.x))));
            o0.y = fmaf(q3, p1.w, fmaf(q2, p1.z, fmaf(q1, p1.y, fmaf(q0, p1.x, bb0.y))));
            o0.z = fmaf(q3, p2.w, fmaf(q2, p2.z, fmaf(q1, p2.y, fmaf(q0, p2.x, bb0.z))));
            o0.w = fmaf(q3, p3.w, fmaf(q2, p3.z, fmaf(q1, p3.y, fmaf(q0, p3.x, bb0.w))));
            o1.x = fmaf(q3, p4.w, fmaf(q2, p4.z, fmaf(q1, p4.y, fmaf(q0, p4.x, bb1.x))));
            o1.y = fmaf(q3, p5.w, fmaf(q2, p5.z, fmaf(q1, p5.y, fmaf(q0, p5.x, bb1.y))));
            o1.z = fmaf(q3, p6.w, fmaf(q2, p6.z, fmaf(q1, p6.y, fmaf(q0, p6.x, bb1.z))));
            o1.w = fmaf(q3, p7.w, fmaf(q2, p7.z, fmaf(q1, p7.y, fmaf(q0, p7.x, bb1.w))));
            float* orow = out + (size_t)(tb + s) * 512;
            nt_store4(orow + 4 * lane, o0);
            nt_store4(orow + 256 + 4 * lane, o1);
        }
    };

    float a0, a1, a2, a3;

    // -------- software pipeline: 8 passes (2 tiles), loads 2 passes ahead --------
    ISSUE_PASS(0, 0);
    ISSUE_PASS(1, 1);
    DOTS_FOLD(0, a0);  ISSUE_PASS(0, 2);
    DOTS_FOLD(1, a1);  ISSUE_PASS(1, 3);
    DOTS_FOLD(0, a2);  ISSUE_PASS(0, 4);
    DOTS_FOLD(1, a3);  ISSUE_PASS(1, 5);
    tile_body(wbase, a0, a1, a2, a3);            // tile0; passes 4,5 in flight
    DOTS_FOLD(0, a0);  ISSUE_PASS(0, 6);
    DOTS_FOLD(1, a1);  ISSUE_PASS(1, 7);
    DOTS_FOLD(0, a2);
    DOTS_FOLD(1, a3);
    tile_body(wbase + 16, a0, a1, a2, a3);       // tile1
}

extern "C" void kernel_launch(void* const* d_in, const int* in_sizes, int n_in,
                              void* d_out, int out_size, void* d_ws, size_t ws_size,
                              hipStream_t stream)
{
    const float* x     = (const float*)d_in[0];
    const float* preW  = (const float*)d_in[1];
    const float* preb  = (const float*)d_in[2];
    const float* wts   = (const float*)d_in[3];
    const float* postW = (const float*)d_in[4];
    const float* postb = (const float*)d_in[5];
    float* out = (float*)d_out;
    const int B = in_sizes[0] / 512;

    // 4 waves/block x 32 samples/wave = 128 samples/block
    k_fused<<<dim3((B + 127) / 128), dim3(256), 0, stream>>>(
        x, preW, preb, wts, postW, postb, out, B);
}

// Round 4
// 50.340 us; speedup vs baseline: 1.0971x; 1.0971x over previous
//
#include <hip/hip_runtime.h>
#include <math.h>

#define PI_F 3.14159265358979323846f

// QuantumProjection — R14: R12 base (best fused, 50.0us), ONE variable flipped:
// nontemporal stores -> plain float4 stores.
// R13 post-mortem: one-shot waves (16 samples) => grid 4096 waves <= residency, so
// turnover/phase-mixing is structurally impossible; but serial phases at full BW
// would be ~30us anyway (66MB read @6.3 + ~6us VALU + 131MB write @7.1). R12's 50us
// budget shows the write phase runs ~30us = 4.4 TB/s vs the harness fill kernel's
// 7.1 TB/s with PLAIN stores. Suspect: NT stores cap write BW. The R10 NT rationale
// (preserve x in L3) is moot: the 512MB poison fill evicts L3 between iterations;
// within-kernel the only cost of plain stores is out evicting x's L3 half-residency
// (FETCH 66 -> ~110-130MB, ~+7us read) vs predicted -10us write.
// Structure unchanged from R12:
//  - block = 4 waves = 64 samples; phase 1 = K1 dot (4 passes x 4 samples) ->
//    angles in 1KB LDS; __syncthreads; phase 2+3 = K2 circuit (16 samples/wave,
//    4 lanes/sample) + out GEMM with 2 coalesced float4 stores/lane/row.
//  - R7: no launch_bounds reg cap. R9: plain loads for x.

typedef float floatx4 __attribute__((ext_vector_type(4)));

static __device__ __forceinline__ void st_store4(float* p, floatx4 v)
{
    *reinterpret_cast<floatx4*>(p) = v;          // plain store (through L2)
}

static __device__ __forceinline__ float fast_tanh(float a)
{
    a = fminf(fmaxf(a, -15.f), 15.f);
    const float e = __expf(2.f * a);
    return (e - 1.f) / (e + 1.f);
}

// wire w lives at bit (3-w) of the 16-amp index
template<int WIRE>
__device__ __forceinline__ void apply1q(float* sr, float* si,
    float u00r, float u00i, float u01r, float u01i,
    float u10r, float u10i, float u11r, float u11i)
{
    constexpr int st = 1 << (3 - WIRE);
#pragma unroll
    for (int i = 0; i < 16; ++i) {
        if (i & st) continue;
        const int j = i | st;
        const float r0 = sr[i], m0 = si[i], r1 = sr[j], m1 = si[j];
        sr[i] = u00r * r0 - u00i * m0 + u01r * r1 - u01i * m1;
        si[i] = u00r * m0 + u00i * r0 + u01r * m1 + u01i * r1;
        sr[j] = u10r * r0 - u10i * m0 + u11r * r1 - u11i * m1;
        si[j] = u10r * m0 + u10i * r0 + u11r * m1 + u11i * r1;
    }
}

template<int CW, int TW>
__device__ __forceinline__ void cnot(float* sr, float* si)
{
    constexpr int cb = 1 << (3 - CW), tb = 1 << (3 - TW);
#pragma unroll
    for (int i = 0; i < 16; ++i) {
        if ((i & cb) && !(i & tb)) {
            const int j = i | tb;
            float t;
            t = sr[i]; sr[i] = sr[j]; sr[j] = t;
            t = si[i]; si[i] = si[j]; si[j] = t;
        }
    }
}

// Wave-uniform gate via v_sin/v_cos (args in (-pi, 2pi): no range reduction needed)
#define APPLY_FAST(L, W) { \
    const float ph = wts[((L) * 4 + (W)) * 3 + 0]; \
    const float th = wts[((L) * 4 + (W)) * 3 + 1]; \
    const float om = wts[((L) * 4 + (W)) * 3 + 2]; \
    const float s_  = __sinf(0.5f * th),        c_  = __cosf(0.5f * th); \
    const float sp_ = __sinf(0.5f * (ph + om)), cp_ = __cosf(0.5f * (ph + om)); \
    const float sq_ = __sinf(0.5f * (ph - om)), cq_ = __cosf(0.5f * (ph - om)); \
    apply1q<W>(sr, si, cp_ * c_, -sp_ * c_, -cq_ * s_, -sq_ * s_, \
                       cq_ * s_, -sq_ * s_, cp_ * c_,  sp_ * c_); }

// Block = 256 threads = 4 waves = 64 samples.
// Phase 1 (per wave, 4 passes of 4 samples): K1 dot + 17-shfl fold -> angles in LDS.
// Phase 2+3 (per wave, 16 samples): K2 circuit (4 lanes/sample) + out GEMM.
__global__ __launch_bounds__(256) void k_fused(
    const float* __restrict__ x,
    const float* __restrict__ preW,
    const float* __restrict__ preb,
    const float* __restrict__ wts,
    const float* __restrict__ postW,
    const float* __restrict__ postb,
    float* __restrict__ out, int B)
{
    const int lane  = threadIdx.x & 63;
    const int wid   = threadIdx.x >> 6;          // wave in block, 0..3
    const int base  = blockIdx.x * 64;           // 64 samples per block
    const int wbase = base + wid * 16;           // this wave's 16 samples
    if (base >= B) return;

    __shared__ float4 angLds[64];                // [sampleLocal] -> 4 angles

    // ---------- Phase 1: angles (K1 structure, 4 passes) ----------
    float4 wA[4], wB[4];
#pragma unroll
    for (int w = 0; w < 4; ++w) {
        wA[w] = *reinterpret_cast<const float4*>(preW + w * 512 + lane * 4);
        wB[w] = *reinterpret_cast<const float4*>(preW + w * 512 + 256 + lane * 4);
    }
    const float4 pb = *reinterpret_cast<const float4*>(preb);

#pragma unroll
    for (int p = 0; p < 4; ++p) {
        const int b0 = wbase + p * 4;

        float4 xa[4], xb[4];
#pragma unroll
        for (int t = 0; t < 4; ++t) {
            const float* xr = x + (size_t)(b0 + t) * 512;
            xa[t] = *reinterpret_cast<const float4*>(xr + lane * 4);
            xb[t] = *reinterpret_cast<const float4*>(xr + 256 + lane * 4);
        }

        float acc[4][4];
#pragma unroll
        for (int t = 0; t < 4; ++t) {
#pragma unroll
            for (int w = 0; w < 4; ++w) {
                acc[t][w] = xa[t].x * wA[w].x + xa[t].y * wA[w].y + xa[t].z * wA[w].z + xa[t].w * wA[w].w
                          + xb[t].x * wB[w].x + xb[t].y * wB[w].y + xb[t].z * wB[w].z + xb[t].w * wB[w].w;
            }
        }

        // 17-shfl fold: lane l (<16) ends with dot for sample (l>>2), wire l&3
        float v[4];
#pragma unroll
        for (int t = 0; t < 4; ++t) {
            float a01 = (lane & 1) ? acc[t][1] : acc[t][0];
            float b01 = (lane & 1) ? acc[t][0] : acc[t][1];
            a01 += __shfl_xor(b01, 1, 64);
            float a23 = (lane & 1) ? acc[t][3] : acc[t][2];
            float b23 = (lane & 1) ? acc[t][2] : acc[t][3];
            a23 += __shfl_xor(b23, 1, 64);
            const float vv = (lane & 2) ? a23 : a01;
            const float uu = (lane & 2) ? a01 : a23;
            v[t] = vv + __shfl_xor(uu, 2, 64);
        }
        float c01 = (lane & 4) ? v[1] : v[0];
        float d01 = (lane & 4) ? v[0] : v[1];
        c01 += __shfl_xor(d01, 4, 64);
        float c23 = (lane & 4) ? v[3] : v[2];
        float d23 = (lane & 4) ? v[2] : v[3];
        c23 += __shfl_xor(d23, 4, 64);
        float m = (lane & 8) ? c23 : c01;
        float n = (lane & 8) ? c01 : c23;
        m += __shfl_xor(n, 8, 64);
        m += __shfl_xor(m, 16, 64);
        m += __shfl_xor(m, 32, 64);

        const float pb01 = (lane & 1) ? pb.y : pb.x;
        const float pb23 = (lane & 1) ? pb.w : pb.z;
        const float pbv  = (lane & 2) ? pb23 : pb01;
        const float angv = fast_tanh(m + pbv) * PI_F;

        if (lane < 16) {
            float* arow = reinterpret_cast<float*>(&angLds[wid * 16 + p * 4 + (lane >> 2)]);
            arow[lane & 3] = angv;               // 16 consecutive floats: conflict-free
        }
    }

    __syncthreads();

    // ---------- Phase 2: circuit (K2 structure verbatim, 16 samples/wave) ----------
    const int sid = lane >> 2;                   // 0..15
    const float4 ang = angLds[wid * 16 + sid];   // 16B rows, 2-way bank alias = free

    // RX embedding: amp[i] = prod_w (c_w or -i s_w); a/2 in (-pi/2,pi/2)
    const float s0 = __sinf(0.5f * ang.x), c0 = __cosf(0.5f * ang.x);
    const float s1 = __sinf(0.5f * ang.y), c1 = __cosf(0.5f * ang.y);
    const float s2 = __sinf(0.5f * ang.z), c2 = __cosf(0.5f * ang.z);
    const float s3 = __sinf(0.5f * ang.w), c3 = __cosf(0.5f * ang.w);

    float sr[16], si[16];
#pragma unroll
    for (int i = 0; i < 16; ++i) {
        const float r = ((i & 8) ? s0 : c0) * ((i & 4) ? s1 : c1)
                      * ((i & 2) ? s2 : c2) * ((i & 1) ? s3 : c3);
        const int mm = (((i >> 3) & 1) + ((i >> 2) & 1) + ((i >> 1) & 1) + (i & 1)) & 3;
        switch (mm) {                // multiply by (-i)^popcount
            case 0:  sr[i] = r;    si[i] = 0.f; break;
            case 1:  sr[i] = 0.f;  si[i] = -r;  break;
            case 2:  sr[i] = -r;   si[i] = 0.f; break;
            default: sr[i] = 0.f;  si[i] = r;   break;
        }
    }

    APPLY_FAST(0, 0); APPLY_FAST(0, 1); APPLY_FAST(0, 2); APPLY_FAST(0, 3);
    cnot<0, 1>(sr, si); cnot<1, 2>(sr, si); cnot<2, 3>(sr, si); cnot<3, 0>(sr, si);
    APPLY_FAST(1, 0); APPLY_FAST(1, 1); APPLY_FAST(1, 2); APPLY_FAST(1, 3);
    cnot<0, 2>(sr, si); cnot<1, 3>(sr, si); cnot<2, 0>(sr, si); cnot<3, 1>(sr, si);

    float z0 = 0.f, z1 = 0.f, z2 = 0.f, z3 = 0.f;
#pragma unroll
    for (int i = 0; i < 16; ++i) {
        const float p = sr[i] * sr[i] + si[i] * si[i];
        z0 += (i & 8) ? -p : p;
        z1 += (i & 4) ? -p : p;
        z2 += (i & 2) ? -p : p;
        z3 += (i & 1) ? -p : p;
    }

    // ---------- Phase 3: out GEMM (16 rows/wave, plain float4 stores) ----------
    const float4* pW4 = reinterpret_cast<const float4*>(postW);   // row o = postW[o][:]
    const float4* pb4 = reinterpret_cast<const float4*>(postb);
    const float4 p0 = pW4[4 * lane + 0], p1 = pW4[4 * lane + 1];
    const float4 p2 = pW4[4 * lane + 2], p3 = pW4[4 * lane + 3];
    const float4 p4 = pW4[4 * (64 + lane) + 0], p5 = pW4[4 * (64 + lane) + 1];
    const float4 p6 = pW4[4 * (64 + lane) + 2], p7 = pW4[4 * (64 + lane) + 3];
    const float4 bb0 = pb4[lane], bb1 = pb4[64 + lane];

#pragma unroll
    for (int s = 0; s < 16; ++s) {
        // sample s's z values live (identically) in lanes [4s .. 4s+3]
        const float q0 = __shfl(z0, s * 4, 64);
        const float q1 = __shfl(z1, s * 4, 64);
        const float q2 = __shfl(z2, s * 4, 64);
        const float q3 = __shfl(z3, s * 4, 64);
        floatx4 o0, o1;
        o0.x = fmaf(q3, p0.w, fmaf(q2, p0.z, fmaf(q1, p0.y, fmaf(q0, p0.x, bb0.x))));
        o0.y = fmaf(q3, p1.w, fmaf(q2, p1.z, fmaf(q1, p1.y, fmaf(q0, p1.x, bb0.y))));
        o0.z = fmaf(q3, p2.w, fmaf(q2, p2.z, fmaf(q1, p2.y, fmaf(q0, p2.x, bb0.z))));
        o0.w = fmaf(q3, p3.w, fmaf(q2, p3.z, fmaf(q1, p3.y, fmaf(q0, p3.x, bb0.w))));
        o1.x = fmaf(q3, p4.w, fmaf(q2, p4.z, fmaf(q1, p4.y, fmaf(q0, p4.x, bb1.x))));
        o1.y = fmaf(q3, p5.w, fmaf(q2, p5.z, fmaf(q1, p5.y, fmaf(q0, p5.x, bb1.y))));
        o1.z = fmaf(q3, p6.w, fmaf(q2, p6.z, fmaf(q1, p6.y, fmaf(q0, p6.x, bb1.z))));
        o1.w = fmaf(q3, p7.w, fmaf(q2, p7.z, fmaf(q1, p7.y, fmaf(q0, p7.x, bb1.w))));
        float* orow = out + (size_t)(wbase + s) * 512;
        st_store4(orow + 4 * lane, o0);          // cols [lane*4, +4)
        st_store4(orow + 256 + 4 * lane, o1);    // cols [256+lane*4, +4)
    }
}

extern "C" void kernel_launch(void* const* d_in, const int* in_sizes, int n_in,
                              void* d_out, int out_size, void* d_ws, size_t ws_size,
                              hipStream_t stream)
{
    const float* x     = (const float*)d_in[0];
    const float* preW  = (const float*)d_in[1];
    const float* preb  = (const float*)d_in[2];
    const float* wts   = (const float*)d_in[3];
    const float* postW = (const float*)d_in[4];
    const float* postb = (const float*)d_in[5];
    float* out = (float*)d_out;
    const int B = in_sizes[0] / 512;

    // 4 waves/block, 64 samples/block
    k_fused<<<dim3((B + 63) / 64), dim3(256), 0, stream>>>(
        x, preW, preb, wts, postW, postb, out, B);
}

// Round 5
// 46.128 us; speedup vs baseline: 1.1973x; 1.0913x over previous
//
#include <hip/hip_runtime.h>
#include <math.h>

#define PI_F 3.14159265358979323846f

// QuantumProjection — R15: R14 base, ONE change: state-SPLIT circuit.
// R14 post-mortem: plain==NT stores (50.3==50.0); serial-phase budget now fits
// exactly: 2 ramp + 10.5 read (FETCH 66MB @6.3) + 18.7 VALU (22% x 85us profiled,
// absolute-cycle counter) + 18.5 write (131MB @7.1) = 49.7 ~= 50.3 measured.
// Memory terms are at stream ceilings; overlap is structurally blocked (all waves
// resident+lockstep, R12). Remaining lever: shrink VALU. Biggest chunk = circuit:
// each lane held the FULL 16-amp state (4-lane groups fully redundant, 128 FMA/gate).
// R15: split the state across the 4-lane group — 4 amps/lane:
//   amp bits: bit3=wire0 -> lane bit1; bit2=wire1 -> lane bit0; bit1=wire2, bit0=wire3 in-lane (k=0..3)
//   Rot wire2/3: in-lane, 32 FMA (was 128). Rot wire0/1: 32 FMA + 8 shfl_xor(2/1)
//   (partner stays inside the 4-lane group). CNOTs: renames / cndmask / 4-shfl.
//   z-reduce: per-lane partials + xor(1)+xor(2) group reduce -> z0..z3 valid in all
//   4 group lanes = EXACT layout phase 3 already expects. Phases 1 & 3 untouched.
// Circuit ~1300 -> ~480 VALU inst/wave; shuffles move to the DS pipe.
// Kept: R7 (no reg cap), R9 (plain x loads), R14 (plain stores == NT).

typedef float floatx4 __attribute__((ext_vector_type(4)));

static __device__ __forceinline__ void st_store4(float* p, floatx4 v)
{
    *reinterpret_cast<floatx4*>(p) = v;
}

static __device__ __forceinline__ float fast_tanh(float a)
{
    a = fminf(fmaxf(a, -15.f), 15.f);
    const float e = __expf(2.f * a);
    return (e - 1.f) / (e + 1.f);
}

// ---- split-state Rot helpers ----
// in-lane Rot on the k-bit ST (2: wire2, 1: wire3); A=pair elem with bit=0, B with bit=1
template<int ST>
__device__ __forceinline__ void rot_inlane(float* ar, float* ai,
    float u00r, float u00i, float u01r, float u01i,
    float u10r, float u10i, float u11r, float u11i)
{
#pragma unroll
    for (int k = 0; k < 4; ++k) {
        if (k & ST) continue;
        const int j = k | ST;
        const float Ar = ar[k], Ai = ai[k], Br = ar[j], Bi = ai[j];
        ar[k] = u00r*Ar - u00i*Ai + u01r*Br - u01i*Bi;
        ai[k] = u00r*Ai + u00i*Ar + u01r*Bi + u01i*Br;
        ar[j] = u10r*Ar - u10i*Ai + u11r*Br - u11i*Bi;
        ai[j] = u10r*Ai + u10i*Ar + u11r*Bi + u11i*Br;
    }
}

// cross-lane Rot: XM = lane xor (2: wire0, 1: wire1); ownB = this lane holds the '1' side.
// ownB=0: new = u00*own + u01*partner ; ownB=1: new = u11*own + u10*partner
template<int XM>
__device__ __forceinline__ void rot_cross(float* ar, float* ai, bool ownB,
    float u00r, float u00i, float u01r, float u01i,
    float u10r, float u10i, float u11r, float u11i)
{
    const float cAr = ownB ? u11r : u00r;
    const float cAi = ownB ? u11i : u00i;
    const float cBr = ownB ? u10r : u01r;
    const float cBi = ownB ? u10i : u01i;
#pragma unroll
    for (int k = 0; k < 4; ++k) {
        const float pr = __shfl_xor(ar[k], XM, 64);
        const float pi = __shfl_xor(ai[k], XM, 64);
        const float vr = ar[k], vi = ai[k];
        ar[k] = cAr*vr - cAi*vi + cBr*pr - cBi*pi;
        ai[k] = cAr*vi + cAi*vr + cBr*pi + cBi*pr;
    }
}

// qml.Rot coefficients (wave-uniform; args in (-pi,2pi): no range reduction)
#define ROT_COEFFS(L, W) \
    const float ph = wts[((L)*4+(W))*3+0]; \
    const float th = wts[((L)*4+(W))*3+1]; \
    const float om = wts[((L)*4+(W))*3+2]; \
    const float s_  = __sinf(0.5f*th),        c_  = __cosf(0.5f*th); \
    const float sp_ = __sinf(0.5f*(ph+om)),   cp_ = __cosf(0.5f*(ph+om)); \
    const float sq_ = __sinf(0.5f*(ph-om)),   cq_ = __cosf(0.5f*(ph-om));

#define U_ARGS cp_*c_, -sp_*c_, -cq_*s_, -sq_*s_, cq_*s_, -sq_*s_, cp_*c_, sp_*c_

// Block = 256 threads = 4 waves = 64 samples.
__global__ __launch_bounds__(256) void k_fused(
    const float* __restrict__ x,
    const float* __restrict__ preW,
    const float* __restrict__ preb,
    const float* __restrict__ wts,
    const float* __restrict__ postW,
    const float* __restrict__ postb,
    float* __restrict__ out, int B)
{
    const int lane  = threadIdx.x & 63;
    const int wid   = threadIdx.x >> 6;          // wave in block, 0..3
    const int base  = blockIdx.x * 64;           // 64 samples per block
    const int wbase = base + wid * 16;           // this wave's 16 samples
    if (base >= B) return;

    __shared__ float4 angLds[64];                // [sampleLocal] -> 4 angles

    // ---------- Phase 1: angles (K1 structure, 4 passes) — unchanged ----------
    float4 wA[4], wB[4];
#pragma unroll
    for (int w = 0; w < 4; ++w) {
        wA[w] = *reinterpret_cast<const float4*>(preW + w * 512 + lane * 4);
        wB[w] = *reinterpret_cast<const float4*>(preW + w * 512 + 256 + lane * 4);
    }
    const float4 pb = *reinterpret_cast<const float4*>(preb);

#pragma unroll
    for (int p = 0; p < 4; ++p) {
        const int b0 = wbase + p * 4;

        float4 xa[4], xb[4];
#pragma unroll
        for (int t = 0; t < 4; ++t) {
            const float* xr = x + (size_t)(b0 + t) * 512;
            xa[t] = *reinterpret_cast<const float4*>(xr + lane * 4);
            xb[t] = *reinterpret_cast<const float4*>(xr + 256 + lane * 4);
        }

        float acc[4][4];
#pragma unroll
        for (int t = 0; t < 4; ++t) {
#pragma unroll
            for (int w = 0; w < 4; ++w) {
                acc[t][w] = xa[t].x * wA[w].x + xa[t].y * wA[w].y + xa[t].z * wA[w].z + xa[t].w * wA[w].w
                          + xb[t].x * wB[w].x + xb[t].y * wB[w].y + xb[t].z * wB[w].z + xb[t].w * wB[w].w;
            }
        }

        float v[4];
#pragma unroll
        for (int t = 0; t < 4; ++t) {
            float a01 = (lane & 1) ? acc[t][1] : acc[t][0];
            float b01 = (lane & 1) ? acc[t][0] : acc[t][1];
            a01 += __shfl_xor(b01, 1, 64);
            float a23 = (lane & 1) ? acc[t][3] : acc[t][2];
            float b23 = (lane & 1) ? acc[t][2] : acc[t][3];
            a23 += __shfl_xor(b23, 1, 64);
            const float vv = (lane & 2) ? a23 : a01;
            const float uu = (lane & 2) ? a01 : a23;
            v[t] = vv + __shfl_xor(uu, 2, 64);
        }
        float c01 = (lane & 4) ? v[1] : v[0];
        float d01 = (lane & 4) ? v[0] : v[1];
        c01 += __shfl_xor(d01, 4, 64);
        float c23 = (lane & 4) ? v[3] : v[2];
        float d23 = (lane & 4) ? v[2] : v[3];
        c23 += __shfl_xor(d23, 4, 64);
        float m = (lane & 8) ? c23 : c01;
        float n = (lane & 8) ? c01 : c23;
        m += __shfl_xor(n, 8, 64);
        m += __shfl_xor(m, 16, 64);
        m += __shfl_xor(m, 32, 64);

        const float pb01 = (lane & 1) ? pb.y : pb.x;
        const float pb23 = (lane & 1) ? pb.w : pb.z;
        const float pbv  = (lane & 2) ? pb23 : pb01;
        const float angv = fast_tanh(m + pbv) * PI_F;

        if (lane < 16) {
            float* arow = reinterpret_cast<float*>(&angLds[wid * 16 + p * 4 + (lane >> 2)]);
            arow[lane & 3] = angv;
        }
    }

    __syncthreads();

    // ---------- Phase 2: SPLIT-STATE circuit (4 amps/lane, 16 samples/wave) ----------
    const int  sid = lane >> 2;                  // sample in wave, 0..15
    const bool lb3 = (lane & 2) != 0;            // amp bit3 (wire0) of this lane's amps
    const bool lb2 = (lane & 1) != 0;            // amp bit2 (wire1)
    const float4 ang = angLds[wid * 16 + sid];

    const float s0 = __sinf(0.5f * ang.x), c0 = __cosf(0.5f * ang.x);
    const float s1 = __sinf(0.5f * ang.y), c1 = __cosf(0.5f * ang.y);
    const float s2 = __sinf(0.5f * ang.z), c2 = __cosf(0.5f * ang.z);
    const float s3 = __sinf(0.5f * ang.w), c3 = __cosf(0.5f * ang.w);

    // RX embedding, split: amp(4r+k) = mhi*(-i)^(lb3+lb2) * low_k*(-i)^(kpop)
    const float mhi = (lb3 ? s0 : c0) * (lb2 ? s1 : c1);
    const float hr  = lb3 ? (lb2 ? -mhi : 0.f) : (lb2 ? 0.f : mhi);
    const float hi  = (lb3 != lb2) ? -mhi : 0.f;
    const float low0 = c2 * c3, low1 = c2 * s3, low2 = s2 * c3, low3 = s2 * s3;

    float ar[4], ai[4];
    ar[0] =  hr * low0;  ai[0] =  hi * low0;     // kpop=0
    ar[1] =  hi * low1;  ai[1] = -hr * low1;     // kpop=1: *( -i )
    ar[2] =  hi * low2;  ai[2] = -hr * low2;     // kpop=1
    ar[3] = -hr * low3;  ai[3] = -hi * low3;     // kpop=2: *( -1 )

    // ---- layer 0: Rot on wires 0..3 ----
    { ROT_COEFFS(0, 0); rot_cross<2>(ar, ai, lb3, U_ARGS); }
    { ROT_COEFFS(0, 1); rot_cross<1>(ar, ai, lb2, U_ARGS); }
    { ROT_COEFFS(0, 2); rot_inlane<2>(ar, ai, U_ARGS); }
    { ROT_COEFFS(0, 3); rot_inlane<1>(ar, ai, U_ARGS); }

    // ---- layer 0 CNOT ring r=1: <0,1>,<1,2>,<2,3>,<3,0> ----
    {   // cnot<0,1>: lanes with bit3 (lb3) take partner(^1)'s amps
#pragma unroll
        for (int k = 0; k < 4; ++k) {
            const float tr = __shfl_xor(ar[k], 1, 64);
            const float ti = __shfl_xor(ai[k], 1, 64);
            ar[k] = lb3 ? tr : ar[k];
            ai[k] = lb3 ? ti : ai[k];
        }
    }
    {   // cnot<1,2>: lanes with bit2 (lb2) swap k-pairs (0,2),(1,3)
        const float t0r = ar[0], t0i = ai[0], t1r = ar[1], t1i = ai[1];
        ar[0] = lb2 ? ar[2] : ar[0];  ai[0] = lb2 ? ai[2] : ai[0];
        ar[1] = lb2 ? ar[3] : ar[1];  ai[1] = lb2 ? ai[3] : ai[1];
        ar[2] = lb2 ? t0r   : ar[2];  ai[2] = lb2 ? t0i   : ai[2];
        ar[3] = lb2 ? t1r   : ar[3];  ai[3] = lb2 ? t1i   : ai[3];
    }
    {   // cnot<2,3>: uniform in-lane swap k2<->k3 (register rename, free)
        float t;
        t = ar[2]; ar[2] = ar[3]; ar[3] = t;
        t = ai[2]; ai[2] = ai[3]; ai[3] = t;
    }
    {   // cnot<3,0>: k in {1,3} exchange across lane^2 (both sides ctrl=1 -> plain swap)
        ar[1] = __shfl_xor(ar[1], 2, 64);  ai[1] = __shfl_xor(ai[1], 2, 64);
        ar[3] = __shfl_xor(ar[3], 2, 64);  ai[3] = __shfl_xor(ai[3], 2, 64);
    }

    // ---- layer 1: Rot on wires 0..3 ----
    { ROT_COEFFS(1, 0); rot_cross<2>(ar, ai, lb3, U_ARGS); }
    { ROT_COEFFS(1, 1); rot_cross<1>(ar, ai, lb2, U_ARGS); }
    { ROT_COEFFS(1, 2); rot_inlane<2>(ar, ai, U_ARGS); }
    { ROT_COEFFS(1, 3); rot_inlane<1>(ar, ai, U_ARGS); }

    // ---- layer 1 CNOT ring r=2: <0,2>,<1,3>,<2,0>,<3,1> ----
    {   // cnot<0,2>: lanes with bit3 swap k-pairs (0,2),(1,3)
        const float t0r = ar[0], t0i = ai[0], t1r = ar[1], t1i = ai[1];
        ar[0] = lb3 ? ar[2] : ar[0];  ai[0] = lb3 ? ai[2] : ai[0];
        ar[1] = lb3 ? ar[3] : ar[1];  ai[1] = lb3 ? ai[3] : ai[1];
        ar[2] = lb3 ? t0r   : ar[2];  ai[2] = lb3 ? t0i   : ai[2];
        ar[3] = lb3 ? t1r   : ar[3];  ai[3] = lb3 ? t1i   : ai[3];
    }
    {   // cnot<1,3>: lanes with bit2 swap k-pairs (0,1),(2,3)
        const float t0r = ar[0], t0i = ai[0], t2r = ar[2], t2i = ai[2];
        ar[0] = lb2 ? ar[1] : ar[0];  ai[0] = lb2 ? ai[1] : ai[0];
        ar[1] = lb2 ? t0r   : ar[1];  ai[1] = lb2 ? t0i   : ai[1];
        ar[2] = lb2 ? ar[3] : ar[2];  ai[2] = lb2 ? ai[3] : ai[2];
        ar[3] = lb2 ? t2r   : ar[3];  ai[3] = lb2 ? t2i   : ai[3];
    }
    {   // cnot<2,0>: k in {2,3} exchange across lane^2
        ar[2] = __shfl_xor(ar[2], 2, 64);  ai[2] = __shfl_xor(ai[2], 2, 64);
        ar[3] = __shfl_xor(ar[3], 2, 64);  ai[3] = __shfl_xor(ai[3], 2, 64);
    }
    {   // cnot<3,1>: k in {1,3} exchange across lane^1
        ar[1] = __shfl_xor(ar[1], 1, 64);  ai[1] = __shfl_xor(ai[1], 1, 64);
        ar[3] = __shfl_xor(ar[3], 1, 64);  ai[3] = __shfl_xor(ai[3], 1, 64);
    }

    // ---- PauliZ expvals: per-lane partials + 4-lane group xor-reduce ----
    const float p0 = ar[0]*ar[0] + ai[0]*ai[0];
    const float p1 = ar[1]*ar[1] + ai[1]*ai[1];
    const float p2 = ar[2]*ar[2] + ai[2]*ai[2];
    const float p3 = ar[3]*ar[3] + ai[3]*ai[3];
    const float s01 = p0 + p1, s23 = p2 + p3;
    const float sum = s01 + s23;
    float z0 = lb3 ? -sum : sum;                 // sign by amp bit3 (wire0)
    float z1 = lb2 ? -sum : sum;                 // sign by amp bit2 (wire1)
    float z2 = s01 - s23;                        // sign by k bit1 (wire2)
    float z3 = (p0 - p1) + (p2 - p3);            // sign by k bit0 (wire3)
    z0 += __shfl_xor(z0, 1, 64);  z0 += __shfl_xor(z0, 2, 64);
    z1 += __shfl_xor(z1, 1, 64);  z1 += __shfl_xor(z1, 2, 64);
    z2 += __shfl_xor(z2, 1, 64);  z2 += __shfl_xor(z2, 2, 64);
    z3 += __shfl_xor(z3, 1, 64);  z3 += __shfl_xor(z3, 2, 64);
    // now all 4 lanes of group sid hold the full z0..z3 of sample sid (same as R14)

    // ---------- Phase 3: out GEMM (unchanged) ----------
    const float4* pW4 = reinterpret_cast<const float4*>(postW);
    const float4* pb4 = reinterpret_cast<const float4*>(postb);
    const float4 q0w = pW4[4 * lane + 0], q1w = pW4[4 * lane + 1];
    const float4 q2w = pW4[4 * lane + 2], q3w = pW4[4 * lane + 3];
    const float4 q4w = pW4[4 * (64 + lane) + 0], q5w = pW4[4 * (64 + lane) + 1];
    const float4 q6w = pW4[4 * (64 + lane) + 2], q7w = pW4[4 * (64 + lane) + 3];
    const float4 bb0 = pb4[lane], bb1 = pb4[64 + lane];

#pragma unroll
    for (int s = 0; s < 16; ++s) {
        const float q0 = __shfl(z0, s * 4, 64);
        const float q1 = __shfl(z1, s * 4, 64);
        const float q2 = __shfl(z2, s * 4, 64);
        const float q3 = __shfl(z3, s * 4, 64);
        floatx4 o0, o1;
        o0.x = fmaf(q3, q0w.w, fmaf(q2, q0w.z, fmaf(q1, q0w.y, fmaf(q0, q0w.x, bb0.x))));
        o0.y = fmaf(q3, q1w.w, fmaf(q2, q1w.z, fmaf(q1, q1w.y, fmaf(q0, q1w.x, bb0.y))));
        o0.z = fmaf(q3, q2w.w, fmaf(q2, q2w.z, fmaf(q1, q2w.y, fmaf(q0, q2w.x, bb0.z))));
        o0.w = fmaf(q3, q3w.w, fmaf(q2, q3w.z, fmaf(q1, q3w.y, fmaf(q0, q3w.x, bb0.w))));
        o1.x = fmaf(q3, q4w.w, fmaf(q2, q4w.z, fmaf(q1, q4w.y, fmaf(q0, q4w.x, bb1.x))));
        o1.y = fmaf(q3, q5w.w, fmaf(q2, q5w.z, fmaf(q1, q5w.y, fmaf(q0, q5w.x, bb1.y))));
        o1.z = fmaf(q3, q6w.w, fmaf(q2, q6w.z, fmaf(q1, q6w.y, fmaf(q0, q6w.x, bb1.z))));
        o1.w = fmaf(q3, q7w.w, fmaf(q2, q7w.z, fmaf(q1, q7w.y, fmaf(q0, q7w.x, bb1.w))));
        float* orow = out + (size_t)(wbase + s) * 512;
        st_store4(orow + 4 * lane, o0);
        st_store4(orow + 256 + 4 * lane, o1);
    }
}

extern "C" void kernel_launch(void* const* d_in, const int* in_sizes, int n_in,
                              void* d_out, int out_size, void* d_ws, size_t ws_size,
                              hipStream_t stream)
{
    const float* x     = (const float*)d_in[0];
    const float* preW  = (const float*)d_in[1];
    const float* preb  = (const float*)d_in[2];
    const float* wts   = (const float*)d_in[3];
    const float* postW = (const float*)d_in[4];
    const float* postb = (const float*)d_in[5];
    float* out = (float*)d_out;
    const int B = in_sizes[0] / 512;

    // 4 waves/block, 64 samples/block
    k_fused<<<dim3((B + 63) / 64), dim3(256), 0, stream>>>(
        x, preW, preb, wts, postW, postb, out, B);
}